// Round 15
// baseline (798.192 us; speedup 1.0000x reference)
//
#include <hip/hip_runtime.h>
#include <hip/hip_fp16.h>

#define NTOK 1024
#define INF  1024
#define NH   16
#define DH   64
#define BDIM 512
#define NMEM 8192
#define OUTF 1024
#define NWRD 16   // 512 bits = 16 u32

typedef _Float16 f16x8 __attribute__((ext_vector_type(8)));
typedef float    f32x4 __attribute__((ext_vector_type(4)));
typedef int      i32x4 __attribute__((ext_vector_type(4)));

#define GLOAD16(G, L) __builtin_amdgcn_global_load_lds( \
    (const __attribute__((address_space(1))) unsigned int*)(G), \
    (__attribute__((address_space(3))) unsigned int*)(L), 16, 0, 0)

// score/TEMP * log2(e):  cos(pi/2*(1-s/512)) == sin(pi/2 * s/512), s = count
__device__ inline float score2(float s) {
  return 144.2695040889f * __sinf(s * 0.0030679615757712823f);
}

// ---------------- K1: q = x @ Wq^T + bq (f32, 64x64 tile) ----------------
__global__ __launch_bounds__(256) void k_qgemm(const float* __restrict__ x,
    const float* __restrict__ Wq, const float* __restrict__ bq, float* __restrict__ q) {
  __shared__ float As[64][17];
  __shared__ float Bs[64][17];
  const int tx = threadIdx.x & 15, ty = threadIdx.x >> 4;
  const int n0 = blockIdx.y * 64, o0 = blockIdx.x * 64;
  const int r = threadIdx.x >> 2, c4 = (threadIdx.x & 3) * 4;
  float acc[4][4] = {};
  for (int k0 = 0; k0 < INF; k0 += 16) {
    float4 av = *(const float4*)&x[(size_t)(n0 + r) * INF + k0 + c4];
    float4 bv = *(const float4*)&Wq[(size_t)(o0 + r) * INF + k0 + c4];
    __syncthreads();               // prev compute done before LDS overwrite
    As[r][c4+0] = av.x; As[r][c4+1] = av.y; As[r][c4+2] = av.z; As[r][c4+3] = av.w;
    Bs[r][c4+0] = bv.x; Bs[r][c4+1] = bv.y; Bs[r][c4+2] = bv.z; Bs[r][c4+3] = bv.w;
    __syncthreads();
    #pragma unroll
    for (int kk = 0; kk < 16; ++kk) {
      float a[4], b[4];
      #pragma unroll
      for (int i = 0; i < 4; ++i) a[i] = As[ty*4+i][kk];
      #pragma unroll
      for (int j = 0; j < 4; ++j) b[j] = Bs[tx*4+j][kk];
      #pragma unroll
      for (int i = 0; i < 4; ++i)
        #pragma unroll
        for (int j = 0; j < 4; ++j) acc[i][j] += a[i] * b[j];
    }
  }
  #pragma unroll
  for (int i = 0; i < 4; ++i) {
    const int row = n0 + ty*4 + i;
    #pragma unroll
    for (int j = 0; j < 4; ++j) {
      const int col = o0 + tx*4 + j;
      q[(size_t)row * OUTF + col] = acc[i][j] + bq[col];
    }
  }
}

// ---------------- K2: code_i8 = sign(q . bin_proj) as +-1 i8 ---------------
// norm of q doesn't change sign -> skip normalization entirely
__global__ __launch_bounds__(256) void k_code(const float* __restrict__ q,
    const float* __restrict__ bp, signed char* __restrict__ code_i8) {
  const int h = blockIdx.y, n0 = blockIdx.x * 16;
  __shared__ float ql[16][68];
  const int t = threadIdx.x;
  {
    const int r = t >> 4, c = (t & 15) * 4;
    float4 v = *(const float4*)&q[(size_t)(n0 + r) * OUTF + h * 64 + c];
    ql[r][c] = v.x; ql[r][c+1] = v.y; ql[r][c+2] = v.z; ql[r][c+3] = v.w;
  }
  __syncthreads();
  #pragma unroll
  for (int bb = 0; bb < 512; bb += 256) {
    const int b = bb + t;
    float bpv[64];
    const float4* src = (const float4*)&bp[((size_t)h * BDIM + b) * 64];
    #pragma unroll
    for (int j = 0; j < 16; ++j) {
      float4 v = src[j];
      bpv[j*4] = v.x; bpv[j*4+1] = v.y; bpv[j*4+2] = v.z; bpv[j*4+3] = v.w;
    }
    for (int n = 0; n < 16; ++n) {
      float dot = 0.f;
      #pragma unroll
      for (int d = 0; d < 64; ++d) dot += bpv[d] * ql[n][d];
      code_i8[((size_t)h * NTOK + n0 + n) * BDIM + b] = dot > 0.f ? 1 : -1;
    }
  }
}

// -------- K3: weight_matrix -> sign bits (for k_wt) AND +-1 i8 -------------
// w_i8 is written CHUNK-SWIZZLED: 16B chunk c of row m lands at physical
// chunk p=(c&~7)|((c&7)^(m&7)) so k_sim's linear global_load_lds staging +
// swizzled ds_read_b128 is bank-conflict-free (rule: swizzle both sides).
__global__ __launch_bounds__(256) void k_packw(const float* __restrict__ w,
    unsigned* __restrict__ wp, signed char* __restrict__ w_i8) {
  const int row  = blockIdx.x * 4 + (threadIdx.x >> 6);
  const int lane = threadIdx.x & 63;
  const float* src = w + (size_t)row * BDIM;
  unsigned my = 0;
  #pragma unroll
  for (int kk = 0; kk < 8; ++kk) {
    float v = src[kk * 64 + lane];
    const int c = kk * 4 + (lane >> 4);
    const int p = (c & ~7) | ((c & 7) ^ (row & 7));
    w_i8[(size_t)row * BDIM + p * 16 + (lane & 15)] = v > 0.f ? 1 : -1;
    unsigned long long m = __ballot(v > 0.f);
    if ((lane >> 1) == kk) my = (lane & 1) ? (unsigned)(m >> 32) : (unsigned)m;
  }
  if (lane < 16) wp[(size_t)row * NWRD + lane] = my;
}

// ---------------- K3b: transpose bin_inv [h][d][b] -> binT [h][b][d] -------
__global__ __launch_bounds__(256) void k_binT(const float* __restrict__ binv,
                                              float* __restrict__ bT) {
  const int h = blockIdx.y, b0 = blockIdx.x * 64;
  __shared__ float tl[64][65];
  const int t = threadIdx.x;
  #pragma unroll
  for (int i = 0; i < 4; ++i) {
    int fi = t + 256 * i;
    int d = fi >> 4, b = (fi & 15) * 4;
    float4 v = *(const float4*)&binv[((size_t)h * DH + d) * BDIM + b0 + b];
    tl[d][b] = v.x; tl[d][b+1] = v.y; tl[d][b+2] = v.z; tl[d][b+3] = v.w;
  }
  __syncthreads();
  #pragma unroll
  for (int i = 0; i < 4; ++i) {
    int fo = t + 256 * i;
    int bb = fo >> 4, dd = (fo & 15) * 4;
    float4 v = { tl[dd][bb], tl[dd+1][bb], tl[dd+2][bb], tl[dd+3][bb] };
    *(float4*)&bT[((size_t)h * BDIM + b0 + bb) * DH + dd] = v;
  }
}

// ------- K4: expand bits -> f16 wt [hg][b][m] (+-1), PRE-SWIZZLED ----------
// Within each 128B (64-m) window, 16B chunk g stores logical chunk g^(b&7),
// so stageF's linear global_load_lds + swizzled ds_read are conflict-free.
__global__ __launch_bounds__(256) void k_wt(const unsigned* __restrict__ wp,
    unsigned short* __restrict__ wt, int h0) {
  const int hg = blockIdx.z, h = h0 + hg;
  const int b0 = blockIdx.y * 64, m0 = blockIdx.x * 256;
  __shared__ unsigned bits[256][2];
  const int t = threadIdx.x;
  const unsigned* src = wp + (size_t)(h * NMEM + m0 + t) * NWRD + (b0 >> 5);
  bits[t][0] = src[0]; bits[t][1] = src[1];
  __syncthreads();
  const int b = t >> 2, ms = (t & 3) * 64;
  const int wd = b >> 5, sh = b & 31;
  const int bx7 = b & 7;
  unsigned short* dst = wt + ((size_t)hg * BDIM + b0 + b) * NMEM + m0 + ms;
  #pragma unroll
  for (int g = 0; g < 8; ++g) {
    const int pg = g ^ bx7;
    const int j = ms + g * 8;
    ushort4 v0, v1;
    v0.x = ((bits[j+0][wd] >> sh) & 1) ? 0x3C00 : 0xBC00;
    v0.y = ((bits[j+1][wd] >> sh) & 1) ? 0x3C00 : 0xBC00;
    v0.z = ((bits[j+2][wd] >> sh) & 1) ? 0x3C00 : 0xBC00;
    v0.w = ((bits[j+3][wd] >> sh) & 1) ? 0x3C00 : 0xBC00;
    v1.x = ((bits[j+4][wd] >> sh) & 1) ? 0x3C00 : 0xBC00;
    v1.y = ((bits[j+5][wd] >> sh) & 1) ? 0x3C00 : 0xBC00;
    v1.z = ((bits[j+6][wd] >> sh) & 1) ? 0x3C00 : 0xBC00;
    v1.w = ((bits[j+7][wd] >> sh) & 1) ? 0x3C00 : 0xBC00;
    *(ushort4*)&dst[pg * 8]     = v0;
    *(ushort4*)&dst[pg * 8 + 4] = v1;
  }
}

// ------- K5: two-pass sim+exp -> attn f16 (EXACT R13 config: 32 rows) ------
// Pass 1: stage w_i8 (GLOAD) + i8 MFMA + running rowmax (no stores).
// Pass 2: recompute + exp (direct __sinf) -> Pls -> coalesced pre-swizzled
// f16x8 stores under the next tile's DMA. 2-barrier proven skeleton.
// Softmax 1/Z cancels in the later per-head L2-normalize -> numerator only.
__global__ __launch_bounds__(512, 2) void k_sim(const signed char* __restrict__ code_i8,
    const signed char* __restrict__ w_i8, unsigned short* __restrict__ attn,
    int h0, int gmask, int gshift) {
  const int bid = (int)blockIdx.x;
  const int hg = bid & gmask, h = h0 + hg;      // XCD = bid%8 = h%8 (convoy)
  const int n0 = (bid >> gshift) * 32;
  const int t = threadIdx.x, lane = t & 63, wid = t >> 6;
  __shared__ __align__(16) signed char Bls[128 * 512];   // 64KB B tile
  __shared__ __align__(16) _Float16 Pls[32][136];        // 8.5KB, padded
  __shared__ int smaxl[32];
  if (t < 32) smaxl[t] = -(1 << 30);
  const int rg = wid >> 2, mg = wid & 3;
  // A frags: row = n0 + rg*16 + (lane&15), k = kk*64 + (lane>>4)*16
  i32x4 afrag[8];
  #pragma unroll
  for (int kk = 0; kk < 8; ++kk)
    afrag[kk] = *(const i32x4*)(code_i8 +
        ((size_t)h * NTOK + n0 + rg * 16 + (lane & 15)) * BDIM +
        kk * 64 + (lane >> 4) * 16);
  const signed char* wb = w_i8 + (size_t)h * NMEM * BDIM + (size_t)t * 16;
  signed char* const d0 = &Bls[wid * 1024];     // wave-uniform LDS base
  int vmax[4] = {-(1 << 30), -(1 << 30), -(1 << 30), -(1 << 30)};
  // ---------------- PASS 1: rowmax only (no stores) ----------------
  for (int tile = 0; tile < 64; ++tile) {       // 128 m per tile
    const signed char* s = wb + (size_t)tile * 128 * BDIM;
    __syncthreads();                  // previous tile fully consumed
    #pragma unroll
    for (int seg = 0; seg < 8; ++seg)
      GLOAD16(s + seg * 8192, d0 + seg * 8192);
    __syncthreads();                  // drains vmcnt -> tile ready
    #pragma unroll
    for (int msub = 0; msub < 2; ++msub) {
      const signed char* bls = &Bls[(mg * 32 + msub * 16 + (lane & 15)) * 512];
      i32x4 acc = {};
      #pragma unroll
      for (int kk = 0; kk < 8; ++kk) {
        const int c = kk * 4 + (lane >> 4);
        const int p = (c & ~7) | ((c & 7) ^ (lane & 7));
        i32x4 b = *(const i32x4*)(bls + p * 16);
        acc = __builtin_amdgcn_mfma_i32_16x16x64_i8(afrag[kk], b, acc, 0, 0, 0);
      }
      #pragma unroll
      for (int j = 0; j < 4; ++j) vmax[j] = max(vmax[j], acc[j]);
    }
  }
  #pragma unroll
  for (int j = 0; j < 4; ++j) {
    int v = vmax[j];
    #pragma unroll
    for (int s = 1; s < 16; s <<= 1) v = max(v, __shfl_xor(v, s));
    if ((lane & 15) == 0)
      atomicMax(&smaxl[rg * 16 + (lane >> 4) * 4 + j], v);
  }
  __syncthreads();                     // smaxl final
  float sm[4];
  #pragma unroll
  for (int j = 0; j < 4; ++j)
    sm[j] = score2((float)smaxl[rg * 16 + (lane >> 4) * 4 + j]);
  // store-phase decode (per thread): one 16B chunk of one Pls row
  const int srow = t >> 4, sg = t & 15;
  unsigned short* const sdst = attn + ((size_t)hg * NTOK + n0 + srow) * NMEM;
  const int spc = ((sg & 7) ^ (srow & 7)) * 8 + (sg >> 3) * 64;  // swizzled
  // ---------------- PASS 2: recompute + exp -> attn ----------------
  for (int tile = 0; tile < 64; ++tile) {
    const signed char* s = wb + (size_t)tile * 128 * BDIM;
    __syncthreads();                  // Bls consumed, Pls(t-1) written
    #pragma unroll
    for (int seg = 0; seg < 8; ++seg)
      GLOAD16(s + seg * 8192, d0 + seg * 8192);
    if (tile > 0) {                   // store Pls(t-1) while DMA in flight
      f16x8 pv = *(const f16x8*)&Pls[srow][sg * 8];
      *(f16x8*)(sdst + (size_t)(tile - 1) * 128 + spc) = pv;
    }
    __syncthreads();                  // DMA done + Pls reads done
    #pragma unroll
    for (int msub = 0; msub < 2; ++msub) {
      const signed char* bls = &Bls[(mg * 32 + msub * 16 + (lane & 15)) * 512];
      i32x4 acc = {};
      #pragma unroll
      for (int kk = 0; kk < 8; ++kk) {
        const int c = kk * 4 + (lane >> 4);
        const int p = (c & ~7) | ((c & 7) ^ (lane & 7));
        i32x4 b = *(const i32x4*)(bls + p * 16);
        acc = __builtin_amdgcn_mfma_i32_16x16x64_i8(afrag[kk], b, acc, 0, 0, 0);
      }
      const int col = mg * 32 + msub * 16 + (lane & 15);
      #pragma unroll
      for (int j = 0; j < 4; ++j) {
        const int r0 = rg * 16 + (lane >> 4) * 4 + j;
        float pr = exp2f(score2((float)acc[j]) - sm[j]);
        Pls[r0][col] = (_Float16)pr;
      }
    }
  }
  __syncthreads();                     // last Pls written
  {                                    // epilogue: store tile 63
    f16x8 pv = *(const f16x8*)&Pls[srow][sg * 8];
    *(f16x8*)(sdst + (size_t)63 * 128 + spc) = pv;
  }
}

// ------- K6: o1^T = (attn @ wt)^T, f16 MFMA GEMM, 128x256 tile -------------
// Re-tiling of the proven 2-barrier skeleton: A-panel re-reads halve
// (16 blocks/head), 64 MFMA/wave per 6-GLOAD barrier pair (was 32 per 4).
// Both operands pre-swizzled in global; linear global_load_lds staging;
// XOR-deswizzled ds_read_b128 (same algebra, row&7 == lane&7 preserved).
__global__ __launch_bounds__(512, 2) void k_stageF(const unsigned short* __restrict__ attn,
    const unsigned short* __restrict__ wt, float* __restrict__ o1t,
    int gmask, int gshift) {
  __shared__ __align__(16) _Float16 Al[128][64];   // 16KB
  __shared__ __align__(16) _Float16 Bl[256][64];   // 32KB
  const int wg = (int)blockIdx.x;
  const int hg = wg & gmask;                   // XCD = wg%8 = hg%8
  const int rest = wg >> gshift;
  const int nt = rest & 7, bt = rest >> 3;     // nt in [0,8), bt in [0,2)
  const int n0 = nt * 128, b0 = bt * 256;
  const int t = threadIdx.x;
  const int lane = t & 63, wid = t >> 6;
  const int wm = wid >> 2, wn = wid & 3;       // 2 row-groups x 4 col-groups
  f32x4 acc[4][4];
  #pragma unroll
  for (int i = 0; i < 4; ++i)
    #pragma unroll
    for (int j = 0; j < 4; ++j) acc[i][j] = (f32x4){0.f, 0.f, 0.f, 0.f};

  const unsigned short* ag = attn + ((size_t)hg * NTOK + n0 + 16*wid + (lane >> 3)) * NMEM + (lane & 7) * 8;
  const unsigned short* bg = wt   + ((size_t)hg * BDIM + b0 + 32*wid + (lane >> 3)) * NMEM + (lane & 7) * 8;
  _Float16* al0 = &Al[16 * wid][0];            // wave-uniform LDS bases
  _Float16* bl0 = &Bl[32 * wid][0];

  for (int k0 = 0; k0 < NMEM; k0 += 64) {
    __syncthreads();                    // previous tile fully consumed
    GLOAD16(ag + k0,             al0);
    GLOAD16(ag + k0 +  8 * NMEM, al0 +  8 * 64);
    GLOAD16(bg + k0,             bl0);
    GLOAD16(bg + k0 +  8 * NMEM, bl0 +  8 * 64);
    GLOAD16(bg + k0 + 16 * NMEM, bl0 + 16 * 64);
    GLOAD16(bg + k0 + 24 * NMEM, bl0 + 24 * 64);
    __syncthreads();                    // drains vmcnt -> tile ready
    #pragma unroll
    for (int kk = 0; kk < 64; kk += 32) {
      const int phys = (((kk >> 3) + (lane >> 4)) ^ (lane & 7)) * 8;
      f16x8 af[4], bf[4];
      #pragma unroll
      for (int fm = 0; fm < 4; ++fm)
        af[fm] = *(const f16x8*)&Al[wm*64 + fm*16 + (lane & 15)][phys];
      #pragma unroll
      for (int fn = 0; fn < 4; ++fn)
        bf[fn] = *(const f16x8*)&Bl[wn*64 + fn*16 + (lane & 15)][phys];
      #pragma unroll
      for (int fm = 0; fm < 4; ++fm)
        #pragma unroll
        for (int fn = 0; fn < 4; ++fn)
          acc[fm][fn] = __builtin_amdgcn_mfma_f32_16x16x32_f16(af[fm], bf[fn], acc[fm][fn], 0, 0, 0);
    }
  }
  #pragma unroll
  for (int fm = 0; fm < 4; ++fm) {
    const int rowb = n0 + wm*64 + fm*16 + (lane >> 4) * 4;   // C: row=(l>>4)*4+reg
    #pragma unroll
    for (int fn = 0; fn < 4; ++fn) {
      const int col = b0 + wn*64 + fn*16 + (lane & 15);      // C: col=l&15
      *(f32x4*)&o1t[((size_t)hg * BDIM + col) * NTOK + rowb] = acc[fm][fn];
    }
  }
}

// ------- K7: out[n][h*64+d] = normalize_d( o1 . bin_inv ) ------------------
__global__ __launch_bounds__(256) void k_proj(const float* __restrict__ o1t,
    const float* __restrict__ bT, float* __restrict__ o2, int h0) {
  const int hg = blockIdx.y, h = h0 + hg;
  const int n0 = blockIdx.x * 64;
  __shared__ float bl[128][68];
  __shared__ float ol[128][68];
  __shared__ float outl[64][68];
  __shared__ float nrm[64];
  const int t = threadIdx.x;
  const int tx = t & 15, ty = t >> 4;
  float acc[4][4] = {};
  for (int c = 0; c < 4; ++c) {
    const int bb0 = c * 128;
    __syncthreads();
    #pragma unroll
    for (int i = 0; i < 8; ++i) {
      int fi = t + 256 * i;
      int rr = fi >> 4, cc = (fi & 15) * 4;
      *(float4*)&bl[rr][cc] = *(const float4*)&bT[((size_t)h * BDIM + bb0 + rr) * DH + cc];
      *(float4*)&ol[rr][cc] = *(const float4*)&o1t[((size_t)hg * BDIM + bb0 + rr) * NTOK + n0 + cc];
    }
    __syncthreads();
    for (int bb = 0; bb < 128; ++bb) {
      float4 bd = *(const float4*)&bl[bb][tx * 4];
      float4 on = *(const float4*)&ol[bb][ty * 4];
      float ai[4] = {on.x, on.y, on.z, on.w};
      float bj[4] = {bd.x, bd.y, bd.z, bd.w};
      #pragma unroll
      for (int i = 0; i < 4; ++i)
        #pragma unroll
        for (int j = 0; j < 4; ++j) acc[i][j] += ai[i] * bj[j];
    }
  }
  __syncthreads();
  #pragma unroll
  for (int i = 0; i < 4; ++i)
    #pragma unroll
    for (int j = 0; j < 4; ++j) outl[ty*4 + i][tx*4 + j] = acc[i][j];
  __syncthreads();
  if (t < 64) {
    float s = 0.f;
    #pragma unroll
    for (int d = 0; d < 64; ++d) { float v = outl[t][d]; s += v * v; }
    nrm[t] = 1.f / sqrtf(s);
  }
  __syncthreads();
  {
    const int n = t >> 2, dg = (t & 3) * 16;
    #pragma unroll
    for (int j = 0; j < 16; ++j)
      o2[(size_t)(n0 + n) * OUTF + h * 64 + dg + j] = outl[n][dg + j] * nrm[n];
  }
}

// ------- K8: LayerNorm over 1024 features ----------------------------------
__global__ __launch_bounds__(256) void k_ln(const float* __restrict__ o2,
    const float* __restrict__ lnw, const float* __restrict__ lnb, float* __restrict__ out) {
  const int n = blockIdx.x, t = threadIdx.x;
  __shared__ float red[4];
  float4 v = *(const float4*)&o2[(size_t)n * OUTF + t * 4];
  float s = v.x + v.y + v.z + v.w;
  const int lane = t & 63, wid = t >> 6;
  #pragma unroll
  for (int off = 32; off; off >>= 1) s += __shfl_down(s, off);
  if (lane == 0) red[wid] = s;
  __syncthreads();
  const float mu = (red[0] + red[1] + red[2] + red[3]) * (1.f / 1024.f);
  float4 d = {v.x - mu, v.y - mu, v.z - mu, v.w - mu};
  float s2 = d.x*d.x + d.y*d.y + d.z*d.z + d.w*d.w;
  #pragma unroll
  for (int off = 32; off; off >>= 1) s2 += __shfl_down(s2, off);
  __syncthreads();
  if (lane == 0) red[wid] = s2;
  __syncthreads();
  const float var = (red[0] + red[1] + red[2] + red[3]) * (1.f / 1024.f);
  const float inv = 1.f / sqrtf(var + 1e-5f);
  float4 w = *(const float4*)&lnw[t * 4];
  float4 b = *(const float4*)&lnb[t * 4];
  float4 o = { d.x*inv*w.x + b.x, d.y*inv*w.y + b.y,
               d.z*inv*w.z + b.z, d.w*inv*w.w + b.w };
  *(float4*)&out[(size_t)n * OUTF + t * 4] = o;
}

extern "C" void kernel_launch(void* const* d_in, const int* in_sizes, int n_in,
                              void* d_out, int out_size, void* d_ws, size_t ws_size,
                              hipStream_t stream) {
  (void)in_sizes; (void)n_in; (void)out_size;
  const float* x    = (const float*)d_in[0];
  const float* Wq   = (const float*)d_in[1];
  const float* bq   = (const float*)d_in[2];
  const float* bp   = (const float*)d_in[3];
  const float* binv = (const float*)d_in[4];
  const float* wm   = (const float*)d_in[5];
  const float* lnw  = (const float*)d_in[6];
  const float* lnb  = (const float*)d_in[7];
  float* outp = (float*)d_out;

  char* ws = (char*)d_ws;
  size_t off = 0;
  auto carve = [&](size_t bytes) -> char* {
    char* p = ws + off;
    off += (bytes + 255) & ~(size_t)255;
    return p;
  };
  float*       q       = (float*)      carve((size_t)NTOK * OUTF * 4);
  signed char* code_i8 = (signed char*)carve((size_t)NH * NTOK * BDIM);
  unsigned*    wpk     = (unsigned*)   carve((size_t)NH * NMEM * NWRD * 4);
  signed char* w_i8    = (signed char*)carve((size_t)NH * NMEM * BDIM);
  float*       bT      = (float*)      carve((size_t)NH * BDIM * DH * 4);
  float*       o2      = (float*)      carve((size_t)NTOK * OUTF * 4);
  const size_t fixed = off;
  const size_t per = ((size_t)BDIM * NMEM * 2 + 256)    // wt
                   + ((size_t)NTOK * NMEM * 2 + 256)    // attn f16
                   + ((size_t)BDIM * NTOK * 4 + 256);   // o1t
  int G = 16;
  while (G > 1 && fixed + (size_t)G * per > ws_size) G >>= 1;
  unsigned short* wt   = (unsigned short*)carve((size_t)G * BDIM * NMEM * 2);
  unsigned short* attn = (unsigned short*)carve((size_t)G * NTOK * NMEM * 2);
  float*          o1t  = (float*)         carve((size_t)G * BDIM * NTOK * 4);
  const int gshift = __builtin_ctz(G);

  k_qgemm<<<dim3(16, 16), 256, 0, stream>>>(x, Wq, bq, q);
  k_code <<<dim3(64, 16), 256, 0, stream>>>(q, bp, code_i8);
  k_packw<<<dim3(NH * NMEM / 4), 256, 0, stream>>>(wm, wpk, w_i8);
  k_binT <<<dim3(8, 16), 256, 0, stream>>>(binv, bT);
  for (int h0 = 0; h0 < NH; h0 += G) {
    k_wt    <<<dim3(32, 8, G), 256, 0, stream>>>(wpk, wt, h0);
    k_sim   <<<dim3(32 * G),   512, 0, stream>>>(code_i8, w_i8, attn, h0, G - 1, gshift);
    k_stageF<<<dim3(16 * G),   512, 0, stream>>>(attn, wt, o1t, G - 1, gshift);
    k_proj  <<<dim3(16, G),    256, 0, stream>>>(o1t, bT, o2, h0);
  }
  k_ln<<<dim3(NTOK), 256, 0, stream>>>(o2, lnw, lnb, outp);
}

// Round 17
// 708.312 us; speedup vs baseline: 1.1269x; 1.1269x over previous
//
#include <hip/hip_runtime.h>
#include <hip/hip_fp16.h>

#define NTOK 1024
#define INF  1024
#define NH   16
#define DH   64
#define BDIM 512
#define NMEM 8192
#define OUTF 1024
#define NWRD 16   // 512 bits = 16 u32

typedef _Float16 f16x8 __attribute__((ext_vector_type(8)));
typedef float    f32x4 __attribute__((ext_vector_type(4)));
typedef int      i32x4 __attribute__((ext_vector_type(4)));

#define GLOAD16(G, L) __builtin_amdgcn_global_load_lds( \
    (const __attribute__((address_space(1))) unsigned int*)(G), \
    (__attribute__((address_space(3))) unsigned int*)(L), 16, 0, 0)

// score/TEMP * log2(e):  cos(pi/2*(1-s/512)) == sin(pi/2 * s/512), s = count
__device__ inline float score2(float s) {
  return 144.2695040889f * __sinf(s * 0.0030679615757712823f);
}

// ---------------- K1: q = x @ Wq^T + bq (f32, 64x64 tile) ----------------
__global__ __launch_bounds__(256) void k_qgemm(const float* __restrict__ x,
    const float* __restrict__ Wq, const float* __restrict__ bq, float* __restrict__ q) {
  __shared__ float As[64][17];
  __shared__ float Bs[64][17];
  const int tx = threadIdx.x & 15, ty = threadIdx.x >> 4;
  const int n0 = blockIdx.y * 64, o0 = blockIdx.x * 64;
  const int r = threadIdx.x >> 2, c4 = (threadIdx.x & 3) * 4;
  float acc[4][4] = {};
  for (int k0 = 0; k0 < INF; k0 += 16) {
    float4 av = *(const float4*)&x[(size_t)(n0 + r) * INF + k0 + c4];
    float4 bv = *(const float4*)&Wq[(size_t)(o0 + r) * INF + k0 + c4];
    __syncthreads();               // prev compute done before LDS overwrite
    As[r][c4+0] = av.x; As[r][c4+1] = av.y; As[r][c4+2] = av.z; As[r][c4+3] = av.w;
    Bs[r][c4+0] = bv.x; Bs[r][c4+1] = bv.y; Bs[r][c4+2] = bv.z; Bs[r][c4+3] = bv.w;
    __syncthreads();
    #pragma unroll
    for (int kk = 0; kk < 16; ++kk) {
      float a[4], b[4];
      #pragma unroll
      for (int i = 0; i < 4; ++i) a[i] = As[ty*4+i][kk];
      #pragma unroll
      for (int j = 0; j < 4; ++j) b[j] = Bs[tx*4+j][kk];
      #pragma unroll
      for (int i = 0; i < 4; ++i)
        #pragma unroll
        for (int j = 0; j < 4; ++j) acc[i][j] += a[i] * b[j];
    }
  }
  #pragma unroll
  for (int i = 0; i < 4; ++i) {
    const int row = n0 + ty*4 + i;
    #pragma unroll
    for (int j = 0; j < 4; ++j) {
      const int col = o0 + tx*4 + j;
      q[(size_t)row * OUTF + col] = acc[i][j] + bq[col];
    }
  }
}

// ---------------- K2: code_i8 = sign(q . bin_proj) as +-1 i8 ---------------
// norm of q doesn't change sign -> skip normalization entirely
__global__ __launch_bounds__(256) void k_code(const float* __restrict__ q,
    const float* __restrict__ bp, signed char* __restrict__ code_i8) {
  const int h = blockIdx.y, n0 = blockIdx.x * 16;
  __shared__ float ql[16][68];
  const int t = threadIdx.x;
  {
    const int r = t >> 4, c = (t & 15) * 4;
    float4 v = *(const float4*)&q[(size_t)(n0 + r) * OUTF + h * 64 + c];
    ql[r][c] = v.x; ql[r][c+1] = v.y; ql[r][c+2] = v.z; ql[r][c+3] = v.w;
  }
  __syncthreads();
  #pragma unroll
  for (int bb = 0; bb < 512; bb += 256) {
    const int b = bb + t;
    float bpv[64];
    const float4* src = (const float4*)&bp[((size_t)h * BDIM + b) * 64];
    #pragma unroll
    for (int j = 0; j < 16; ++j) {
      float4 v = src[j];
      bpv[j*4] = v.x; bpv[j*4+1] = v.y; bpv[j*4+2] = v.z; bpv[j*4+3] = v.w;
    }
    for (int n = 0; n < 16; ++n) {
      float dot = 0.f;
      #pragma unroll
      for (int d = 0; d < 64; ++d) dot += bpv[d] * ql[n][d];
      code_i8[((size_t)h * NTOK + n0 + n) * BDIM + b] = dot > 0.f ? 1 : -1;
    }
  }
}

// -------- K3: weight_matrix -> sign bits (for k_wtb) AND +-1 i8 ------------
// w_i8 is written CHUNK-SWIZZLED: 16B chunk c of row m lands at physical
// chunk p=(c&~7)|((c&7)^(m&7)) so k_sim's linear global_load_lds staging +
// swizzled ds_read_b128 is bank-conflict-free (rule: swizzle both sides).
__global__ __launch_bounds__(256) void k_packw(const float* __restrict__ w,
    unsigned* __restrict__ wp, signed char* __restrict__ w_i8) {
  const int row  = blockIdx.x * 4 + (threadIdx.x >> 6);
  const int lane = threadIdx.x & 63;
  const float* src = w + (size_t)row * BDIM;
  unsigned my = 0;
  #pragma unroll
  for (int kk = 0; kk < 8; ++kk) {
    float v = src[kk * 64 + lane];
    const int c = kk * 4 + (lane >> 4);
    const int p = (c & ~7) | ((c & 7) ^ (row & 7));
    w_i8[(size_t)row * BDIM + p * 16 + (lane & 15)] = v > 0.f ? 1 : -1;
    unsigned long long m = __ballot(v > 0.f);
    if ((lane >> 1) == kk) my = (lane & 1) ? (unsigned)(m >> 32) : (unsigned)m;
  }
  if (lane < 16) wp[(size_t)row * NWRD + lane] = my;
}

// ---- K3c: bit-transpose wpk[m][b-bits] -> wtb[h][b][m-bits] ---------------
// wtb row = 8192 m-bits = 128 u64. ballot bit l = lane l = m offset, and
// u64 little-endian byte k holds m-bits 8k..8k+7 -> byte m>>3, bit m&7.
__global__ __launch_bounds__(256) void k_wtb(const unsigned* __restrict__ wp,
    unsigned long long* __restrict__ wtb) {
  const int h = blockIdx.y;                    // head
  const int mg = blockIdx.x;                   // 128 groups of 64 m
  const int lane = threadIdx.x & 63, wv = threadIdx.x >> 6;
  const int m = mg * 64 + lane;
  #pragma unroll
  for (int wi = 0; wi < 4; ++wi) {
    const int wd = wv * 4 + wi;                // u32 word 0..15 (32 b each)
    const unsigned word = wp[(size_t)(h * NMEM + m) * NWRD + wd];
    for (int j = 0; j < 32; ++j) {
      unsigned long long msk = __ballot((word >> j) & 1);
      if (lane == 0)
        wtb[((size_t)h * BDIM + wd * 32 + j) * 128 + mg] = msk;
    }
  }
}

// ---------------- K3b: transpose bin_inv [h][d][b] -> binT [h][b][d] -------
__global__ __launch_bounds__(256) void k_binT(const float* __restrict__ binv,
                                              float* __restrict__ bT) {
  const int h = blockIdx.y, b0 = blockIdx.x * 64;
  __shared__ float tl[64][65];
  const int t = threadIdx.x;
  #pragma unroll
  for (int i = 0; i < 4; ++i) {
    int fi = t + 256 * i;
    int d = fi >> 4, b = (fi & 15) * 4;
    float4 v = *(const float4*)&binv[((size_t)h * DH + d) * BDIM + b0 + b];
    tl[d][b] = v.x; tl[d][b+1] = v.y; tl[d][b+2] = v.z; tl[d][b+3] = v.w;
  }
  __syncthreads();
  #pragma unroll
  for (int i = 0; i < 4; ++i) {
    int fo = t + 256 * i;
    int bb = fo >> 4, dd = (fo & 15) * 4;
    float4 v = { tl[dd][bb], tl[dd+1][bb], tl[dd+2][bb], tl[dd+3][bb] };
    *(float4*)&bT[((size_t)h * BDIM + b0 + bb) * DH + dd] = v;
  }
}

// ------- K5: two-pass sim+exp -> attn f16 (EXACT R13 config) ---------------
// Pass 1: stage w_i8 (GLOAD) + i8 MFMA + running rowmax over ALL memories.
// Pass 2: recompute + exp (direct __sinf) -> Pls -> coalesced pre-swizzled
// f16x8 stores under the next tile's DMA. 2-barrier proven skeleton.
// Softmax 1/Z cancels in the later per-head L2-normalize -> numerator only.
__global__ __launch_bounds__(512, 2) void k_sim(const signed char* __restrict__ code_i8,
    const signed char* __restrict__ w_i8, unsigned short* __restrict__ attn,
    int h0, int gmask, int gshift) {
  const int bid = (int)blockIdx.x;
  const int hg = bid & gmask, h = h0 + hg;      // XCD = bid%8 = h%8 (convoy)
  const int n0 = (bid >> gshift) * 32;
  const int t = threadIdx.x, lane = t & 63, wid = t >> 6;
  __shared__ __align__(16) signed char Bls[128 * 512];   // 64KB B tile
  __shared__ __align__(16) _Float16 Pls[32][136];        // 8.5KB, padded
  __shared__ int smaxl[32];
  if (t < 32) smaxl[t] = -(1 << 30);
  const int rg = wid >> 2, mg = wid & 3;
  // A frags: row = n0 + rg*16 + (lane&15), k = kk*64 + (lane>>4)*16
  i32x4 afrag[8];
  #pragma unroll
  for (int kk = 0; kk < 8; ++kk)
    afrag[kk] = *(const i32x4*)(code_i8 +
        ((size_t)h * NTOK + n0 + rg * 16 + (lane & 15)) * BDIM +
        kk * 64 + (lane >> 4) * 16);
  const signed char* wb = w_i8 + (size_t)h * NMEM * BDIM + (size_t)t * 16;
  signed char* const d0 = &Bls[wid * 1024];     // wave-uniform LDS base
  int vmax[4] = {-(1 << 30), -(1 << 30), -(1 << 30), -(1 << 30)};
  // ---------------- PASS 1: rowmax only (no stores) ----------------
  for (int tile = 0; tile < 64; ++tile) {       // 128 m per tile
    const signed char* s = wb + (size_t)tile * 128 * BDIM;
    __syncthreads();                  // previous tile fully consumed
    #pragma unroll
    for (int seg = 0; seg < 8; ++seg)
      GLOAD16(s + seg * 8192, d0 + seg * 8192);
    __syncthreads();                  // drains vmcnt -> tile ready
    #pragma unroll
    for (int msub = 0; msub < 2; ++msub) {
      const signed char* bls = &Bls[(mg * 32 + msub * 16 + (lane & 15)) * 512];
      i32x4 acc = {};
      #pragma unroll
      for (int kk = 0; kk < 8; ++kk) {
        const int c = kk * 4 + (lane >> 4);
        const int p = (c & ~7) | ((c & 7) ^ (lane & 7));
        i32x4 b = *(const i32x4*)(bls + p * 16);
        acc = __builtin_amdgcn_mfma_i32_16x16x64_i8(afrag[kk], b, acc, 0, 0, 0);
      }
      #pragma unroll
      for (int j = 0; j < 4; ++j) vmax[j] = max(vmax[j], acc[j]);
    }
  }
  #pragma unroll
  for (int j = 0; j < 4; ++j) {
    int v = vmax[j];
    #pragma unroll
    for (int s = 1; s < 16; s <<= 1) v = max(v, __shfl_xor(v, s));
    if ((lane & 15) == 0)
      atomicMax(&smaxl[rg * 16 + (lane >> 4) * 4 + j], v);
  }
  __syncthreads();                     // smaxl final
  float sm[4];
  #pragma unroll
  for (int j = 0; j < 4; ++j)
    sm[j] = score2((float)smaxl[rg * 16 + (lane >> 4) * 4 + j]);
  // store-phase decode (per thread): one 16B chunk of one Pls row
  const int srow = t >> 4, sg = t & 15;
  unsigned short* const sdst = attn + ((size_t)hg * NTOK + n0 + srow) * NMEM;
  const int spc = ((sg & 7) ^ (srow & 7)) * 8 + (sg >> 3) * 64;  // swizzled
  // ---------------- PASS 2: recompute + exp -> attn ----------------
  for (int tile = 0; tile < 64; ++tile) {
    const signed char* s = wb + (size_t)tile * 128 * BDIM;
    __syncthreads();                  // Bls consumed, Pls(t-1) written
    #pragma unroll
    for (int seg = 0; seg < 8; ++seg)
      GLOAD16(s + seg * 8192, d0 + seg * 8192);
    if (tile > 0) {                   // store Pls(t-1) while DMA in flight
      f16x8 pv = *(const f16x8*)&Pls[srow][sg * 8];
      *(f16x8*)(sdst + (size_t)(tile - 1) * 128 + spc) = pv;
    }
    __syncthreads();                  // DMA done + Pls reads done
    #pragma unroll
    for (int msub = 0; msub < 2; ++msub) {
      const signed char* bls = &Bls[(mg * 32 + msub * 16 + (lane & 15)) * 512];
      i32x4 acc = {};
      #pragma unroll
      for (int kk = 0; kk < 8; ++kk) {
        const int c = kk * 4 + (lane >> 4);
        const int p = (c & ~7) | ((c & 7) ^ (lane & 7));
        i32x4 b = *(const i32x4*)(bls + p * 16);
        acc = __builtin_amdgcn_mfma_i32_16x16x64_i8(afrag[kk], b, acc, 0, 0, 0);
      }
      const int col = mg * 32 + msub * 16 + (lane & 15);
      #pragma unroll
      for (int j = 0; j < 4; ++j) {
        const int r0 = rg * 16 + (lane >> 4) * 4 + j;
        float pr = exp2f(score2((float)acc[j]) - sm[j]);
        Pls[r0][col] = (_Float16)pr;
      }
    }
  }
  __syncthreads();                     // last Pls written
  {                                    // epilogue: store tile 63
    f16x8 pv = *(const f16x8*)&Pls[srow][sg * 8];
    *(f16x8*)(sdst + (size_t)63 * 128 + spc) = pv;
  }
}

// ------- K6: o1^T = (attn @ W)^T, f16 MFMA, 128x128; B from BITS -----------
// B operand is +-1: expand from bit-transposed wtb via 4KB LDS LUT
// (byte -> 8 f16). Kills the 268MB wt tensor, its producer kernel, and
// half of this kernel's DMA. A staged exactly as R13 (pre-swizzled attn,
// linear global_load_lds, XOR-deswizzled ds_read_b128).
__global__ __launch_bounds__(512, 2) void k_stageF(const unsigned short* __restrict__ attn,
    const unsigned long long* __restrict__ wtb, float* __restrict__ o1t,
    int gmask, int gshift) {
  __shared__ __align__(16) _Float16 Al[128][64];   // 16KB
  __shared__ __align__(16) _Float16 lut[256][8];   // 4KB byte->8 f16 (+-1)
  const int t = threadIdx.x;
  if (t < 256) {
    #pragma unroll
    for (int j = 0; j < 8; ++j)
      lut[t][j] = ((t >> j) & 1) ? (_Float16)1.f : (_Float16)-1.f;
  }
  const int wg = (int)blockIdx.x;
  const int hg = wg & gmask;                   // XCD = wg%8 = hg%8
  const int rest = wg >> gshift;
  const int nt = rest & 7, bt = rest >> 3;
  const int n0 = nt * 128, b0 = bt * 128;
  const int lane = t & 63, wid = t >> 6;
  const int wm = wid >> 2, wn = wid & 3;
  f32x4 acc[4][2];
  #pragma unroll
  for (int i = 0; i < 4; ++i)
    #pragma unroll
    for (int j = 0; j < 2; ++j) acc[i][j] = (f32x4){0.f, 0.f, 0.f, 0.f};

  const unsigned short* ag = attn + ((size_t)hg * NTOK + n0 + 16*wid + (lane >> 3)) * NMEM + (lane & 7) * 8;
  _Float16* al0 = &Al[16 * wid][0];            // wave-uniform LDS base
  // B bit rows for fn=0,1: brow = b0 + wn*32 + fn*16 + (lane&15)
  const unsigned long long* wb0 = wtb + ((size_t)hg * BDIM + b0 + wn * 32 + (lane & 15)) * 128;
  const unsigned long long* wb1 = wb0 + 16 * 128;

  for (int k0 = 0; k0 < NMEM; k0 += 64) {
    const unsigned long long bits0 = wb0[k0 >> 6];   // 64 m-bits for fn=0
    const unsigned long long bits1 = wb1[k0 >> 6];   // 64 m-bits for fn=1
    __syncthreads();                    // previous tile consumed (+LUT ready)
    GLOAD16(ag + k0,            al0);
    GLOAD16(ag + k0 + 8 * NMEM, al0 + 8 * 64);
    __syncthreads();                    // drains vmcnt -> tile ready
    #pragma unroll
    for (int kk = 0; kk < 64; kk += 32) {
      const int phys = (((kk >> 3) + (lane >> 4)) ^ (lane & 7)) * 8;
      const int sh = kk + (lane >> 4) * 8;           // byte-aligned shift
      f16x8 af[4], bf[2];
      #pragma unroll
      for (int fm = 0; fm < 4; ++fm)
        af[fm] = *(const f16x8*)&Al[wm*64 + fm*16 + (lane & 15)][phys];
      bf[0] = *(const f16x8*)&lut[(unsigned)(bits0 >> sh) & 0xFFu][0];
      bf[1] = *(const f16x8*)&lut[(unsigned)(bits1 >> sh) & 0xFFu][0];
      #pragma unroll
      for (int fm = 0; fm < 4; ++fm)
        #pragma unroll
        for (int fn = 0; fn < 2; ++fn)
          acc[fm][fn] = __builtin_amdgcn_mfma_f32_16x16x32_f16(af[fm], bf[fn], acc[fm][fn], 0, 0, 0);
    }
  }
  #pragma unroll
  for (int fm = 0; fm < 4; ++fm) {
    const int rowb = n0 + wm*64 + fm*16 + (lane >> 4) * 4;   // C: row=(l>>4)*4+reg
    #pragma unroll
    for (int fn = 0; fn < 2; ++fn) {
      const int col = b0 + wn*32 + fn*16 + (lane & 15);      // C: col=l&15
      *(f32x4*)&o1t[((size_t)hg * BDIM + col) * NTOK + rowb] = acc[fm][fn];
    }
  }
}

// ------- K7: out[n][h*64+d] = normalize_d( o1 . bin_inv ) ------------------
__global__ __launch_bounds__(256) void k_proj(const float* __restrict__ o1t,
    const float* __restrict__ bT, float* __restrict__ o2, int h0) {
  const int hg = blockIdx.y, h = h0 + hg;
  const int n0 = blockIdx.x * 64;
  __shared__ float bl[128][68];
  __shared__ float ol[128][68];
  __shared__ float outl[64][68];
  __shared__ float nrm[64];
  const int t = threadIdx.x;
  const int tx = t & 15, ty = t >> 4;
  float acc[4][4] = {};
  for (int c = 0; c < 4; ++c) {
    const int bb0 = c * 128;
    __syncthreads();
    #pragma unroll
    for (int i = 0; i < 8; ++i) {
      int fi = t + 256 * i;
      int rr = fi >> 4, cc = (fi & 15) * 4;
      *(float4*)&bl[rr][cc] = *(const float4*)&bT[((size_t)h * BDIM + bb0 + rr) * DH + cc];
      *(float4*)&ol[rr][cc] = *(const float4*)&o1t[((size_t)hg * BDIM + bb0 + rr) * NTOK + n0 + cc];
    }
    __syncthreads();
    for (int bb = 0; bb < 128; ++bb) {
      float4 bd = *(const float4*)&bl[bb][tx * 4];
      float4 on = *(const float4*)&ol[bb][ty * 4];
      float ai[4] = {on.x, on.y, on.z, on.w};
      float bj[4] = {bd.x, bd.y, bd.z, bd.w};
      #pragma unroll
      for (int i = 0; i < 4; ++i)
        #pragma unroll
        for (int j = 0; j < 4; ++j) acc[i][j] += ai[i] * bj[j];
    }
  }
  __syncthreads();
  #pragma unroll
  for (int i = 0; i < 4; ++i)
    #pragma unroll
    for (int j = 0; j < 4; ++j) outl[ty*4 + i][tx*4 + j] = acc[i][j];
  __syncthreads();
  if (t < 64) {
    float s = 0.f;
    #pragma unroll
    for (int d = 0; d < 64; ++d) { float v = outl[t][d]; s += v * v; }
    nrm[t] = 1.f / sqrtf(s);
  }
  __syncthreads();
  {
    const int n = t >> 2, dg = (t & 3) * 16;
    #pragma unroll
    for (int j = 0; j < 16; ++j)
      o2[(size_t)(n0 + n) * OUTF + h * 64 + dg + j] = outl[n][dg + j] * nrm[n];
  }
}

// ------- K8: LayerNorm over 1024 features ----------------------------------
__global__ __launch_bounds__(256) void k_ln(const float* __restrict__ o2,
    const float* __restrict__ lnw, const float* __restrict__ lnb, float* __restrict__ out) {
  const int n = blockIdx.x, t = threadIdx.x;
  __shared__ float red[4];
  float4 v = *(const float4*)&o2[(size_t)n * OUTF + t * 4];
  float s = v.x + v.y + v.z + v.w;
  const int lane = t & 63, wid = t >> 6;
  #pragma unroll
  for (int off = 32; off; off >>= 1) s += __shfl_down(s, off);
  if (lane == 0) red[wid] = s;
  __syncthreads();
  const float mu = (red[0] + red[1] + red[2] + red[3]) * (1.f / 1024.f);
  float4 d = {v.x - mu, v.y - mu, v.z - mu, v.w - mu};
  float s2 = d.x*d.x + d.y*d.y + d.z*d.z + d.w*d.w;
  #pragma unroll
  for (int off = 32; off; off >>= 1) s2 += __shfl_down(s2, off);
  __syncthreads();
  if (lane == 0) red[wid] = s2;
  __syncthreads();
  const float var = (red[0] + red[1] + red[2] + red[3]) * (1.f / 1024.f);
  const float inv = 1.f / sqrtf(var + 1e-5f);
  float4 w = *(const float4*)&lnw[t * 4];
  float4 b = *(const float4*)&lnb[t * 4];
  float4 o = { d.x*inv*w.x + b.x, d.y*inv*w.y + b.y,
               d.z*inv*w.z + b.z, d.w*inv*w.w + b.w };
  *(float4*)&out[(size_t)n * OUTF + t * 4] = o;
}

extern "C" void kernel_launch(void* const* d_in, const int* in_sizes, int n_in,
                              void* d_out, int out_size, void* d_ws, size_t ws_size,
                              hipStream_t stream) {
  (void)in_sizes; (void)n_in; (void)out_size;
  const float* x    = (const float*)d_in[0];
  const float* Wq   = (const float*)d_in[1];
  const float* bq   = (const float*)d_in[2];
  const float* bp   = (const float*)d_in[3];
  const float* binv = (const float*)d_in[4];
  const float* wm   = (const float*)d_in[5];
  const float* lnw  = (const float*)d_in[6];
  const float* lnb  = (const float*)d_in[7];
  float* outp = (float*)d_out;

  char* ws = (char*)d_ws;
  size_t off = 0;
  auto carve = [&](size_t bytes) -> char* {
    char* p = ws + off;
    off += (bytes + 255) & ~(size_t)255;
    return p;
  };
  float*       q       = (float*)      carve((size_t)NTOK * OUTF * 4);
  signed char* code_i8 = (signed char*)carve((size_t)NH * NTOK * BDIM);
  unsigned*    wpk     = (unsigned*)   carve((size_t)NH * NMEM * NWRD * 4);
  signed char* w_i8    = (signed char*)carve((size_t)NH * NMEM * BDIM);
  unsigned long long* wtb = (unsigned long long*)carve((size_t)NH * BDIM * 128 * 8);
  float*       bT      = (float*)      carve((size_t)NH * BDIM * DH * 4);
  float*       o2      = (float*)      carve((size_t)NTOK * OUTF * 4);
  const size_t fixed = off;
  const size_t per = ((size_t)NTOK * NMEM * 2 + 256)    // attn f16
                   + ((size_t)BDIM * NTOK * 4 + 256);   // o1t
  int G = 16;
  while (G > 1 && fixed + (size_t)G * per > ws_size) G >>= 1;
  unsigned short* attn = (unsigned short*)carve((size_t)G * NTOK * NMEM * 2);
  float*          o1t  = (float*)         carve((size_t)G * BDIM * NTOK * 4);
  const int gshift = __builtin_ctz(G);

  k_qgemm<<<dim3(16, 16), 256, 0, stream>>>(x, Wq, bq, q);
  k_code <<<dim3(64, 16), 256, 0, stream>>>(q, bp, code_i8);
  k_packw<<<dim3(NH * NMEM / 4), 256, 0, stream>>>(wm, wpk, w_i8);
  k_wtb  <<<dim3(128, NH), 256, 0, stream>>>(wpk, wtb);
  k_binT <<<dim3(8, 16), 256, 0, stream>>>(binv, bT);
  for (int h0 = 0; h0 < NH; h0 += G) {
    k_sim   <<<dim3(32 * G),   512, 0, stream>>>(code_i8, w_i8, attn, h0, G - 1, gshift);
    k_stageF<<<dim3(32 * G),   512, 0, stream>>>(attn, wtb + (size_t)h0 * BDIM * 128, o1t, G - 1, gshift);
    k_proj  <<<dim3(16, G),    256, 0, stream>>>(o1t, bT, o2, h0);
  }
  k_ln<<<dim3(NTOK), 256, 0, stream>>>(o2, lnw, lnb, outp);
}